// Round 14
// baseline (163.070 us; speedup 1.0000x reference)
//
#include <hip/hip_runtime.h>
#include <math.h>

constexpr int BATCH = 8;
constexpr int SEQ   = 1024;
constexpr int DM    = 256;
constexpr int DF    = 2048;
constexpr int NH    = 8;
constexpr int HDIM  = 32;
constexpr int ROWS  = BATCH * SEQ;    // 8192
constexpr float NEGV = -9e15f;
constexpr float EPSV = 1e-5f;
constexpr float QSCALE = 0.2550351822f;   // 1/sqrt(32) * log2(e)
constexpr float LOG2E  = 1.44269504f;

typedef __attribute__((ext_vector_type(8))) short short8;
typedef __attribute__((ext_vector_type(4))) float f32x4;

static __device__ __forceinline__ ushort f2bf(float f) {
    unsigned x = __float_as_uint(f);
    unsigned r = (x + 0x7fffu + ((x >> 16) & 1u)) >> 16;   // RNE
    return (ushort)r;
}
static __device__ __forceinline__ float bf2f(ushort u) {
    return __uint_as_float((unsigned)u << 16);
}
static __device__ __forceinline__ unsigned cvt_pk_bf16(float lo, float hi) {
    unsigned r;
    asm volatile("v_cvt_pk_bf16_f32 %0, %1, %2" : "=v"(r) : "v"(lo), "v"(hi));
    return r;
}

// ---------------- fused prep: 5-region cast + W_gat transpose-cast + w12 ----------------
struct CastArgs {
    const float* in[5];
    ushort* out[5];
    int n4[5];
};
constexpr int CAST_BLKS = (2097152 + 196608 + 65536 + 524288 + 524288) / 4 / 256;  // 3328

__global__ __launch_bounds__(256) void prep_k(CastArgs a,
                                              const float* __restrict__ W_gat,
                                              const float* __restrict__ a_gat,
                                              ushort* __restrict__ wgTb,
                                              float* __restrict__ w1,
                                              float* __restrict__ w2)
{
    __shared__ float Ts[32][33];
    const int bid = blockIdx.x;
    const int t = threadIdx.x;

    if (bid < CAST_BLKS) {
        int idx = bid * 256 + t;
        #pragma unroll
        for (int r = 0; r < 5; r++) {
            if (idx < a.n4[r]) {
                float4 v = *(const float4*)&a.in[r][(size_t)idx * 4];
                ushort4 o; o.x = f2bf(v.x); o.y = f2bf(v.y); o.z = f2bf(v.z); o.w = f2bf(v.w);
                *(ushort4*)&a.out[r][(size_t)idx * 4] = o;
                return;
            }
            idx -= a.n4[r];
        }
    } else if (bid < CAST_BLKS + 64) {
        const int bb = bid - CAST_BLKS;
        const int r0 = (bb >> 3) * 32, c0 = (bb & 7) * 32;
        const int lr = t >> 3, lc4 = (t & 7) * 4;
        float4 v = *(const float4*)&W_gat[(size_t)(r0 + lr) * DM + c0 + lc4];
        Ts[lr][lc4] = v.x; Ts[lr][lc4 + 1] = v.y; Ts[lr][lc4 + 2] = v.z; Ts[lr][lc4 + 3] = v.w;
        __syncthreads();
        const int oc = t >> 3, or4 = (t & 7) * 4;
        ushort4 o;
        o.x = f2bf(Ts[or4 + 0][oc]); o.y = f2bf(Ts[or4 + 1][oc]);
        o.z = f2bf(Ts[or4 + 2][oc]); o.w = f2bf(Ts[or4 + 3][oc]);
        *(ushort4*)&wgTb[(size_t)(c0 + oc) * DM + r0 + or4] = o;
    } else {
        const int k = (bid - CAST_BLKS - 64) * 4 + (t >> 6);
        const int l = t & 63;
        float4 wv = *(const float4*)&W_gat[(size_t)k * DM + 4 * l];
        float4 a1 = *(const float4*)&a_gat[4 * l];
        float4 a2 = *(const float4*)&a_gat[DM + 4 * l];
        float s1 = wv.x*a1.x + wv.y*a1.y + wv.z*a1.z + wv.w*a1.w;
        float s2 = wv.x*a2.x + wv.y*a2.y + wv.z*a2.z + wv.w*a2.w;
        #pragma unroll
        for (int off = 32; off; off >>= 1) {
            s1 += __shfl_xor(s1, off, 64);
            s2 += __shfl_xor(s2, off, 64);
        }
        if (l == 0) { w1[k] = s1; w2[k] = s2; }
    }
}

// ---------------- f1/f2: wave-per-row, float4 loads (pre-scaled by log2e) ----------------
__global__ __launch_bounds__(256) void f12_k(const float* __restrict__ src,
                                             const float* __restrict__ w1,
                                             const float* __restrict__ w2,
                                             float* __restrict__ f1,
                                             float* __restrict__ f2)
{
    const size_t row = (size_t)blockIdx.x * 4 + (threadIdx.x >> 6);
    const int l = threadIdx.x & 63;
    float4 sv = *(const float4*)&src[row * DM + 4 * l];
    float4 v1 = *(const float4*)&w1[4 * l];
    float4 v2 = *(const float4*)&w2[4 * l];
    float s1 = sv.x*v1.x + sv.y*v1.y + sv.z*v1.z + sv.w*v1.w;
    float s2 = sv.x*v2.x + sv.y*v2.y + sv.z*v2.z + sv.w*v2.w;
    #pragma unroll
    for (int off = 32; off; off >>= 1) {
        s1 += __shfl_xor(s1, off, 64);
        s2 += __shfl_xor(s2, off, 64);
    }
    if (l == 0) { f1[row] = s1 * LOG2E; f2[row] = s2 * LOG2E; }
}

// ---------------- bf16 MFMA GEMM: reg-prefetch + dbuf LDS, bf16 out ----------------
// EP: 1 +bias, 2 +bias,relu, 5 plain, 6 qkv(+bias, Q-scaled)
template<int EP, int BM, int BN>
__global__ __launch_bounds__(256) void gemm_bf(const ushort* __restrict__ A,
                                               const ushort* __restrict__ B,
                                               const float* __restrict__ bias,
                                               ushort* __restrict__ Cb,
                                               int N, int K, int ldB)
{
    __shared__ ushort As[2][BM][40];
    __shared__ ushort Bs[2][BN][40];

    const int t  = threadIdx.x;
    const int m0 = blockIdx.y * BM, n0 = blockIdx.x * BN;
    const int lane = t & 63, lo = lane & 15, hi = lane >> 4;
    const int w = t >> 6;
    constexpr int NI = BM / 32, NJ = BN / 32;
    const int wr = (w >> 1) * (BM / 2);
    const int wc = (w & 1) * (BN / 2);

    const int lrA = (BM == 128) ? (t >> 1) : (t >> 2);
    const int lcA = (BM == 128) ? ((t & 1) * 16) : ((t & 3) * 8);
    const int lrB = (BN == 128) ? (t >> 1) : (t >> 2);
    const int lcB = (BN == 128) ? ((t & 1) * 16) : ((t & 3) * 8);

    f32x4 acc[NI][NJ];
    const f32x4 zero = {0.f, 0.f, 0.f, 0.f};
    #pragma unroll
    for (int i = 0; i < NI; i++)
        #pragma unroll
        for (int j = 0; j < NJ; j++) acc[i][j] = zero;

    const ushort* Ap = A + (size_t)(m0 + lrA) * K + lcA;
    const ushort* Bp = B + (size_t)(n0 + lrB) * ldB + lcB;

    short8 ar0, ar1, br0, br1;
    ar0 = *(const short8*)(Ap);
    if constexpr (BM == 128) ar1 = *(const short8*)(Ap + 8);
    br0 = *(const short8*)(Bp);
    if constexpr (BN == 128) br1 = *(const short8*)(Bp + 8);
    *(short8*)&As[0][lrA][lcA] = ar0;
    if constexpr (BM == 128) *(short8*)&As[0][lrA][lcA + 8] = ar1;
    *(short8*)&Bs[0][lrB][lcB] = br0;
    if constexpr (BN == 128) *(short8*)&Bs[0][lrB][lcB + 8] = br1;

    const int NT = K >> 5;
    for (int it = 0; it < NT; it++) {
        const int cur = it & 1;
        if (it + 1 < NT) {
            const int k0 = (it + 1) << 5;
            ar0 = *(const short8*)(Ap + k0);
            if constexpr (BM == 128) ar1 = *(const short8*)(Ap + k0 + 8);
            br0 = *(const short8*)(Bp + k0);
            if constexpr (BN == 128) br1 = *(const short8*)(Bp + k0 + 8);
        }
        __syncthreads();

        short8 afr[NI], bfr[NJ];
        #pragma unroll
        for (int i = 0; i < NI; i++) afr[i] = *(const short8*)&As[cur][wr + i*16 + lo][hi * 8];
        #pragma unroll
        for (int j = 0; j < NJ; j++) bfr[j] = *(const short8*)&Bs[cur][wc + j*16 + lo][hi * 8];
        #pragma unroll
        for (int i = 0; i < NI; i++)
            #pragma unroll
            for (int j = 0; j < NJ; j++)
                acc[i][j] = __builtin_amdgcn_mfma_f32_16x16x32_bf16(afr[i], bfr[j], acc[i][j], 0, 0, 0);

        if (it + 1 < NT) {
            *(short8*)&As[cur ^ 1][lrA][lcA] = ar0;
            if constexpr (BM == 128) *(short8*)&As[cur ^ 1][lrA][lcA + 8] = ar1;
            *(short8*)&Bs[cur ^ 1][lrB][lcB] = br0;
            if constexpr (BN == 128) *(short8*)&Bs[cur ^ 1][lrB][lcB + 8] = br1;
        }
    }

    #pragma unroll
    for (int j = 0; j < NJ; j++) {
        const int col = n0 + wc + j * 16 + lo;
        float bj = (EP == 1 || EP == 2 || EP == 6) ? bias[col] : 0.f;
        #pragma unroll
        for (int i = 0; i < NI; i++) {
            const int rbase = m0 + wr + i * 16 + hi * 4;
            #pragma unroll
            for (int r = 0; r < 4; r++) {
                float v = acc[i][j][r] + bj;
                if (EP == 2) v = fmaxf(v, 0.f);
                if (EP == 6 && col < DM) v *= QSCALE;
                Cb[(size_t)(rbase + r) * N + col] = f2bf(v);
            }
        }
    }
}

// ---------------- fused GAT: masked online-softmax + PV + elu, 16 rows/block ----------------
// e[i][j] = adj ? f1[i]+f2[j] : NEGV (f1,f2 pre-scaled by log2e); out = elu((P@Wh)/l)
__global__ __launch_bounds__(256) void gat_k(const int* __restrict__ adj,
                                             const float* __restrict__ f1,
                                             const float* __restrict__ f2,
                                             const ushort* __restrict__ WhT,
                                             ushort* __restrict__ out)
{
    __shared__ ushort Ws[256][72];   // WhT tile [d][j_local], linear, padded
    __shared__ int    adjS[16][68];
    __shared__ ushort Ps[16][72];    // P tile, LINEAR col layout
    __shared__ float  f2S[1024];
    __shared__ float  f1S[16];

    const int blk = blockIdx.x;          // 512 blocks x 16 rows
    const int brow0 = blk << 4;
    const int b = brow0 >> 10;
    const size_t bcol = (size_t)b << 10;
    const int t = threadIdx.x;
    const int w = t >> 6, lane = t & 63, lo = lane & 15, hi = lane >> 4;
    const int gsh = lane & 48;

    *(float4*)&f2S[4 * t] = *(const float4*)&f2[bcol + 4 * t];
    if (t < 16) f1S[t] = f1[brow0 + t];

    short8 ones;
    #pragma unroll
    for (int e = 0; e < 8; e++) ones[e] = (short)0x3F80;   // bf16 1.0

    // staging mapping
    const int sd = t >> 3, sc = (t & 7) * 8;      // Ws: 8 passes, 32 d-rows each, 16B/lane
    const int ar = t >> 4, ac = (t & 15) * 4;     // adjS: 16 rows, int4/lane

    short8 wreg[8]; int4 areg;
    auto load = [&](int j0) {
        #pragma unroll
        for (int p = 0; p < 8; p++)
            wreg[p] = *(const short8*)(WhT + (size_t)(p * 32 + sd) * ROWS + bcol + j0 + sc);
        areg = *(const int4*)(adj + (size_t)(brow0 + ar) * SEQ + j0 + ac);
    };
    auto store = [&]() {
        #pragma unroll
        for (int p = 0; p < 8; p++)
            *(short8*)&Ws[p * 32 + sd][sc] = wreg[p];
        *(int4*)&adjS[ar][ac] = areg;
    };

    float m_run[4], l_run[4];
    f32x4 O[4];
    const f32x4 zero = {0.f, 0.f, 0.f, 0.f};
    #pragma unroll
    for (int r = 0; r < 4; r++) { m_run[r] = -3.0e38f; l_run[r] = 0.f; }
    #pragma unroll
    for (int fr = 0; fr < 4; fr++) O[fr] = zero;

    load(0);
    store();

    for (int it = 0; it < 16; it++) {
        __syncthreads();                          // staged tile (+f1S/f2S) visible
        if (it < 15) load((it + 1) << 6);         // prefetch overlaps compute

        const int j0 = it << 6;
        float f1v[4];
        #pragma unroll
        for (int r = 0; r < 4; r++) f1v[r] = f1S[4 * hi + r];
        float S[4][4];
        #pragma unroll
        for (int jt = 0; jt < 4; jt++) {
            const float f2v = f2S[j0 + lo + 16 * jt];
            #pragma unroll
            for (int r = 0; r < 4; r++) {
                int a = adjS[4 * hi + r][lo + 16 * jt];
                S[jt][r] = (a > 0) ? (f1v[r] + f2v) : NEGV;
            }
        }
        // defer-max (all 4 waves compute identical state)
        float mxl[4]; bool any = false;
        #pragma unroll
        for (int r = 0; r < 4; r++) {
            mxl[r] = fmaxf(fmaxf(S[0][r], S[1][r]), fmaxf(S[2][r], S[3][r]));
            any = any || (mxl[r] > m_run[r] + 8.f);
        }
        unsigned long long bal = __ballot(any);
        if ((bal >> gsh) & 0xffffULL) {
            #pragma unroll
            for (int r = 0; r < 4; r++) {
                float mx = mxl[r];
                #pragma unroll
                for (int off = 8; off; off >>= 1) mx = fmaxf(mx, __shfl_xor(mx, off, 16));
                float mnew = fmaxf(m_run[r], mx);
                float sc_ = exp2f(m_run[r] - mnew);
                m_run[r] = mnew;
                l_run[r] *= sc_;
                #pragma unroll
                for (int fr = 0; fr < 4; fr++) O[fr][r] *= sc_;
            }
        }
        // P -> LDS, LINEAR layout (cols lo+16jt); duplicate identical writes across waves are benign
        #pragma unroll
        for (int r = 0; r < 4; r++) {
            const int row = 4 * hi + r;
            unsigned u01 = cvt_pk_bf16(exp2f(S[0][r] - m_run[r]), exp2f(S[1][r] - m_run[r]));
            unsigned u23 = cvt_pk_bf16(exp2f(S[2][r] - m_run[r]), exp2f(S[3][r] - m_run[r]));
            Ps[row][lo]      = (ushort)u01;
            Ps[row][lo + 16] = (ushort)(u01 >> 16);
            Ps[row][lo + 32] = (ushort)u23;
            Ps[row][lo + 48] = (ushort)(u23 >> 16);
        }

        // O += P @ Wh ; l += P @ 1   (Ps rows complete per wave: no barrier)
        f32x4 O2 = zero;
        #pragma unroll
        for (int kt = 0; kt < 2; kt++) {
            short8 aP = *(const short8*)&Ps[lo][kt * 32 + hi * 8];
            #pragma unroll
            for (int fr = 0; fr < 4; fr++) {
                short8 bV = *(const short8*)&Ws[w * 64 + fr * 16 + lo][kt * 32 + hi * 8];
                O[fr] = __builtin_amdgcn_mfma_f32_16x16x32_bf16(aP, bV, O[fr], 0, 0, 0);
            }
            O2 = __builtin_amdgcn_mfma_f32_16x16x32_bf16(aP, ones, O2, 0, 0, 0);
        }
        #pragma unroll
        for (int r = 0; r < 4; r++) l_run[r] += O2[r];

        __syncthreads();                          // all LDS reads done
        if (it < 15) store();                     // overwrite tiles
    }

    #pragma unroll
    for (int r = 0; r < 4; r++) {
        const float inv = 1.0f / l_run[r];
        const size_t row = (size_t)brow0 + 4 * hi + r;
        #pragma unroll
        for (int fr = 0; fr < 4; fr++) {
            float v = O[fr][r] * inv;
            v = v > 0.f ? v : expm1f(v);
            out[row * DM + w * 64 + fr * 16 + lo] = f2bf(v);
        }
    }
}

// ---------------- LayerNorm(a + r)*g + b: wave-per-row ----------------
// MODE 0: a=f32, out=bf16; MODE 1: a=bf16, out=bf16; MODE 2: a=bf16, out=f32
template<int MODE>
__global__ __launch_bounds__(256) void ln_k(const float* __restrict__ af,
                                            const ushort* __restrict__ ab,
                                            const ushort* __restrict__ r,
                                            const float* __restrict__ g,
                                            const float* __restrict__ be,
                                            float* __restrict__ of,
                                            ushort* __restrict__ ob)
{
    const size_t row = (size_t)blockIdx.x * 4 + (threadIdx.x >> 6);
    const int l = threadIdx.x & 63;
    ushort4 rv = *(const ushort4*)&r[row * DM + 4 * l];
    float v0, v1, v2, v3;
    if (MODE == 0) {
        float4 av = *(const float4*)&af[row * DM + 4 * l];
        v0 = av.x + bf2f(rv.x); v1 = av.y + bf2f(rv.y);
        v2 = av.z + bf2f(rv.z); v3 = av.w + bf2f(rv.w);
    } else {
        ushort4 av = *(const ushort4*)&ab[row * DM + 4 * l];
        v0 = bf2f(av.x) + bf2f(rv.x); v1 = bf2f(av.y) + bf2f(rv.y);
        v2 = bf2f(av.z) + bf2f(rv.z); v3 = bf2f(av.w) + bf2f(rv.w);
    }
    float s = (v0 + v1) + (v2 + v3);
    #pragma unroll
    for (int off = 32; off; off >>= 1) s += __shfl_xor(s, off, 64);
    const float mu = s * (1.0f / DM);
    float q = (v0-mu)*(v0-mu) + (v1-mu)*(v1-mu) + (v2-mu)*(v2-mu) + (v3-mu)*(v3-mu);
    #pragma unroll
    for (int off = 32; off; off >>= 1) q += __shfl_xor(q, off, 64);
    const float rs = rsqrtf(q * (1.0f / DM) + EPSV);
    float4 gv = *(const float4*)&g[4 * l];
    float4 bv = *(const float4*)&be[4 * l];
    float o0 = (v0 - mu) * rs * gv.x + bv.x;
    float o1 = (v1 - mu) * rs * gv.y + bv.y;
    float o2 = (v2 - mu) * rs * gv.z + bv.z;
    float o3 = (v3 - mu) * rs * gv.w + bv.w;
    if (MODE == 2) {
        float4 ov; ov.x = o0; ov.y = o1; ov.z = o2; ov.w = o3;
        *(float4*)&of[row * DM + 4 * l] = ov;
    } else {
        ushort4 obv;
        obv.x = f2bf(o0); obv.y = f2bf(o1); obv.z = f2bf(o2); obv.w = f2bf(o3);
        *(ushort4*)&ob[row * DM + 4 * l] = obv;
    }
}

// ---------------- MHA v6: 128 q-rows / block, 8 waves, split K/V staging ----------------
__device__ __forceinline__ int vt_idx(int d, int kv) { return d * 72 + ((d >> 3) & 3) * 16 + kv; }
constexpr int VTSZ = 32 * 72 + 3 * 16 + 8;

__global__ __launch_bounds__(512) void mha_k(const ushort* __restrict__ qkv,
                                             ushort* __restrict__ ctxb)
{
    __shared__ ushort Ks[2][64][40];
    __shared__ ushort Vt[2][VTSZ];
    __shared__ ushort Ps[128][72];

    const int blk = blockIdx.x;
    const int grp = blk & 63, qt = blk >> 6;
    const int h = grp & 7, b = grp >> 3;
    const int i0 = qt << 7;
    const int t = threadIdx.x;
    const int w = t >> 6, lane = t & 63, lo = lane & 15, hi = lane >> 4;
    const int gsh = lane & 48;
    const size_t base = (size_t)b * SEQ * 768;

    const short8 aQ = *(const short8*)(qkv + base + (size_t)(i0 + 16*w + lo) * 768 + h * HDIM + hi * 8);
    short8 ones;
    #pragma unroll
    for (int e = 0; e < 8; e++) ones[e] = (short)0x3F80;

    const int tt = t & 255;
    const int srow = tt >> 2, scb = (tt & 3) << 3;
    const bool isK = t < 256;
    const int vcol = (srow & 32) | ((srow & 15) << 1) | ((srow >> 4) & 1);
    {
        const ushort* p0 = qkv + base + (size_t)srow * 768 + h * HDIM + (isK ? 256 : 512) + scb;
        short8 v0 = *(const short8*)p0;
        if (isK) *(short8*)&Ks[0][srow][scb] = v0;
        else {
            #pragma unroll
            for (int e = 0; e < 8; e++) Vt[0][vt_idx(scb + e, vcol)] = (ushort)v0[e];
        }
    }

    float m_run[4], l_run[4];
    f32x4 O0 = {0.f, 0.f, 0.f, 0.f}, O1 = {0.f, 0.f, 0.f, 0.f};
    #pragma unroll
    for (int r = 0; r < 4; r++) { m_run[r] = -3.0e38f; l_run[r] = 0.f; }
    const f32x4 zero = {0.f, 0.f, 0.f, 0.f};

    short8 reg;
    for (int it = 0; it < 16; it++) {
        const int cur = it & 1;
        if (it < 15)
            reg = *(const short8*)(qkv + base + (size_t)((it + 1) * 64 + srow) * 768
                                   + h * HDIM + (isK ? 256 : 512) + scb);
        __syncthreads();

        f32x4 S[4];
        #pragma unroll
        for (int jt = 0; jt < 4; jt++) {
            short8 bK = *(const short8*)&Ks[cur][16 * jt + lo][hi * 8];
            S[jt] = __builtin_amdgcn_mfma_f32_16x16x32_bf16(aQ, bK, zero, 0, 0, 0);
        }

        float mxl[4];
        bool any = false;
        #pragma unroll
        for (int r = 0; r < 4; r++) {
            mxl[r] = fmaxf(fmaxf(S[0][r], S[1][r]), fmaxf(S[2][r], S[3][r]));
            any = any || (mxl[r] > m_run[r] + 8.f);
        }
        unsigned long long bal = __ballot(any);
        if ((bal >> gsh) & 0xffffULL) {
            #pragma unroll
            for (int r = 0; r < 4; r++) {
                float mx = mxl[r];
                #pragma unroll
                for (int off = 8; off; off >>= 1) mx = fmaxf(mx, __shfl_xor(mx, off, 16));
                float mnew = fmaxf(m_run[r], mx);
                float sc = exp2f(m_run[r] - mnew);
                m_run[r] = mnew;
                l_run[r] *= sc; O0[r] *= sc; O1[r] *= sc;
            }
        }
        #pragma unroll
        for (int r = 0; r < 4; r++) {
            const int row = 16 * w + 4 * hi + r;
            unsigned u01 = cvt_pk_bf16(exp2f(S[0][r] - m_run[r]), exp2f(S[1][r] - m_run[r]));
            unsigned u23 = cvt_pk_bf16(exp2f(S[2][r] - m_run[r]), exp2f(S[3][r] - m_run[r]));
            *(unsigned*)&Ps[row][2 * lo]      = u01;
            *(unsigned*)&Ps[row][32 + 2 * lo] = u23;
        }

        f32x4 O2 = zero;
        #pragma unroll
        for (int kt = 0; kt < 2; kt++) {
            short8 aP  = *(const short8*)&Ps[16 * w + lo][32 * kt + hi * 8];
            short8 bV0 = *(const short8*)&Vt[cur][vt_idx(lo,      32 * kt + hi * 8)];
            short8 bV1 = *(const short8*)&Vt[cur][vt_idx(16 + lo, 32 * kt + hi * 8)];
            O0 = __builtin_amdgcn_mfma_f32_16x16x32_bf16(aP, bV0, O0, 0, 0, 0);
            O1 = __builtin_amdgcn_mfma_f32_16x16x32_bf16(aP, bV1, O1, 0, 0, 0);
            O2 = __builtin_amdgcn_mfma_f32_16x16x32_bf16(aP, ones, O2, 0, 0, 0);
        }
        #pragma unroll
        for (int r = 0; r < 4; r++) l_run[r] += O2[r];

        if (it < 15) {
            if (isK) *(short8*)&Ks[cur ^ 1][srow][scb] = reg;
            else {
                #pragma unroll
                for (int e = 0; e < 8; e++) Vt[cur ^ 1][vt_idx(scb + e, vcol)] = (ushort)reg[e];
            }
        }
    }

    #pragma unroll
    for (int r = 0; r < 4; r++) {
        float inv = 1.0f / l_run[r];
        size_t row = (size_t)b * SEQ + i0 + 16 * w + 4 * hi + r;
        ctxb[row * DM + h * HDIM + lo]      = f2bf(O0[r] * inv);
        ctxb[row * DM + h * HDIM + 16 + lo] = f2bf(O1[r] * inv);
    }
}

extern "C" void kernel_launch(void* const* d_in, const int* in_sizes, int n_in,
                              void* d_out, int out_size, void* d_ws, size_t ws_size,
                              hipStream_t stream)
{
    const float* src        = (const float*)d_in[0];
    const int*   adj        = (const int*)  d_in[1];
    const float* W_gat      = (const float*)d_in[2];
    const float* a_gat      = (const float*)d_in[3];
    const float* in_proj_w  = (const float*)d_in[4];
    const float* in_proj_b  = (const float*)d_in[5];
    const float* out_proj_w = (const float*)d_in[6];
    const float* out_proj_b = (const float*)d_in[7];
    const float* lin1_w     = (const float*)d_in[8];
    const float* lin1_b     = (const float*)d_in[9];
    const float* lin2_w     = (const float*)d_in[10];
    const float* lin2_b     = (const float*)d_in[11];
    const float* ln1_g      = (const float*)d_in[12];
    const float* ln1_b_     = (const float*)d_in[13];
    const float* ln2_g      = (const float*)d_in[14];
    const float* ln2_b_     = (const float*)d_in[15];
    const float* ln3_g      = (const float*)d_in[16];
    const float* ln3_b_     = (const float*)d_in[17];

    char* base = (char*)d_ws;
    const size_t MB = 1024 * 1024;
    ushort* tmpb  = (ushort*)(base + 0 * MB);    // 4 MB
    ushort* qkvb  = (ushort*)(base + 4 * MB);    // 12 MB (then ff1b 32 MB)
    ushort* ff1b  = (ushort*)(base + 4 * MB);
    ushort* srcb  = (ushort*)(base + 36 * MB);   // 4 MB
    ushort* WhTb  = (ushort*)(base + 40 * MB);   // 4 MB ([256][8192])
    ushort* xb    = (ushort*)(base + 44 * MB);   // 4 MB
    ushort* yb    = (ushort*)(base + 48 * MB);   // 4 MB
    ushort* ctxb  = (ushort*)(base + 52 * MB);   // 4 MB
    float*  f1    = (float*) (base + 56 * MB);
    float*  f2    = f1 + ROWS;
    float*  w1    = f2 + ROWS;
    float*  w2    = w1 + DM;
    ushort* wgTb  = (ushort*)(base + 57 * MB);
    ushort* ipwb  = wgTb + 65536;
    ushort* opwb  = ipwb + 196608;
    ushort* l1wb  = opwb + 65536;
    ushort* l2wb  = l1wb + 524288;

    dim3 b256(256);

    CastArgs ca;
    ca.in[0] = src;       ca.out[0] = srcb; ca.n4[0] = 2097152 / 4;
    ca.in[1] = in_proj_w; ca.out[1] = ipwb; ca.n4[1] = 196608 / 4;
    ca.in[2] = out_proj_w;ca.out[2] = opwb; ca.n4[2] = 65536 / 4;
    ca.in[3] = lin1_w;    ca.out[3] = l1wb; ca.n4[3] = 524288 / 4;
    ca.in[4] = lin2_w;    ca.out[4] = l2wb; ca.n4[4] = 524288 / 4;
    prep_k<<<CAST_BLKS + 64 + 64, b256, 0, stream>>>(ca, W_gat, a_gat, wgTb, w1, w2);

    // --- GAT ---
    f12_k<<<ROWS / 4, b256, 0, stream>>>(src, w1, w2, f1, f2);
    gemm_bf<5, 64, 64><<<dim3(ROWS/64, DM/64, 1), b256, 0, stream>>>(wgTb, srcb, nullptr, WhTb,
                                                                     ROWS, DM, DM);
    gat_k<<<ROWS / 16, b256, 0, stream>>>(adj, f1, f2, WhTb, tmpb);
    ln_k<0><<<ROWS / 4, b256, 0, stream>>>(src, nullptr, tmpb, ln1_g, ln1_b_, nullptr, xb);

    // --- MHA ---
    gemm_bf<6, 128, 64><<<dim3(768/64, ROWS/128, 1), b256, 0, stream>>>(xb, ipwb, in_proj_b, qkvb,
                                                                        768, DM, DM);
    mha_k<<<BATCH * NH * (SEQ / 128), dim3(512), 0, stream>>>(qkvb, ctxb);
    gemm_bf<1, 64, 64><<<dim3(DM/64, ROWS/64, 1), b256, 0, stream>>>(ctxb, opwb, out_proj_b, tmpb,
                                                                     DM, DM, DM);
    ln_k<1><<<ROWS / 4, b256, 0, stream>>>(nullptr, xb, tmpb, ln2_g, ln2_b_, nullptr, yb);

    // --- FFN ---
    gemm_bf<2, 128, 128><<<dim3(DF/128, ROWS/128, 1), b256, 0, stream>>>(yb, l1wb, lin1_b, ff1b,
                                                                         DF, DM, DM);
    gemm_bf<1, 64, 64><<<dim3(DM/64, ROWS/64, 1), b256, 0, stream>>>(ff1b, l2wb, lin2_b, tmpb,
                                                                     DM, DF, DF);
    ln_k<2><<<ROWS / 4, b256, 0, stream>>>(nullptr, yb, tmpb, ln3_g, ln3_b_, (float*)d_out, nullptr);
}

// Round 15
// 155.666 us; speedup vs baseline: 1.0476x; 1.0476x over previous
//
#include <hip/hip_runtime.h>
#include <math.h>

constexpr int BATCH = 8;
constexpr int SEQ   = 1024;
constexpr int DM    = 256;
constexpr int DF    = 2048;
constexpr int NH    = 8;
constexpr int HDIM  = 32;
constexpr int ROWS  = BATCH * SEQ;    // 8192
constexpr float NEGV = -9e15f;
constexpr float EPSV = 1e-5f;
constexpr float QSCALE = 0.2550351822f;   // 1/sqrt(32) * log2(e)
constexpr float LOG2E  = 1.44269504f;

typedef __attribute__((ext_vector_type(8))) short short8;
typedef __attribute__((ext_vector_type(4))) float f32x4;

static __device__ __forceinline__ ushort f2bf(float f) {
    unsigned x = __float_as_uint(f);
    unsigned r = (x + 0x7fffu + ((x >> 16) & 1u)) >> 16;   // RNE
    return (ushort)r;
}
static __device__ __forceinline__ float bf2f(ushort u) {
    return __uint_as_float((unsigned)u << 16);
}
static __device__ __forceinline__ unsigned cvt_pk_bf16(float lo, float hi) {
    unsigned r;
    asm volatile("v_cvt_pk_bf16_f32 %0, %1, %2" : "=v"(r) : "v"(lo), "v"(hi));
    return r;
}

// ---------------- fused prep: 5-region cast + W_gat transpose-cast + w12 ----------------
struct CastArgs {
    const float* in[5];
    ushort* out[5];
    int n4[5];
};
constexpr int CAST_BLKS = (2097152 + 196608 + 65536 + 524288 + 524288) / 4 / 256;  // 3328

__global__ __launch_bounds__(256) void prep_k(CastArgs a,
                                              const float* __restrict__ W_gat,
                                              const float* __restrict__ a_gat,
                                              ushort* __restrict__ wgTb,
                                              float* __restrict__ w1,
                                              float* __restrict__ w2)
{
    __shared__ float Ts[32][33];
    const int bid = blockIdx.x;
    const int t = threadIdx.x;

    if (bid < CAST_BLKS) {
        int idx = bid * 256 + t;
        #pragma unroll
        for (int r = 0; r < 5; r++) {
            if (idx < a.n4[r]) {
                float4 v = *(const float4*)&a.in[r][(size_t)idx * 4];
                ushort4 o; o.x = f2bf(v.x); o.y = f2bf(v.y); o.z = f2bf(v.z); o.w = f2bf(v.w);
                *(ushort4*)&a.out[r][(size_t)idx * 4] = o;
                return;
            }
            idx -= a.n4[r];
        }
    } else if (bid < CAST_BLKS + 64) {
        const int bb = bid - CAST_BLKS;
        const int r0 = (bb >> 3) * 32, c0 = (bb & 7) * 32;
        const int lr = t >> 3, lc4 = (t & 7) * 4;
        float4 v = *(const float4*)&W_gat[(size_t)(r0 + lr) * DM + c0 + lc4];
        Ts[lr][lc4] = v.x; Ts[lr][lc4 + 1] = v.y; Ts[lr][lc4 + 2] = v.z; Ts[lr][lc4 + 3] = v.w;
        __syncthreads();
        const int oc = t >> 3, or4 = (t & 7) * 4;
        ushort4 o;
        o.x = f2bf(Ts[or4 + 0][oc]); o.y = f2bf(Ts[or4 + 1][oc]);
        o.z = f2bf(Ts[or4 + 2][oc]); o.w = f2bf(Ts[or4 + 3][oc]);
        *(ushort4*)&wgTb[(size_t)(c0 + oc) * DM + r0 + or4] = o;
    } else {
        const int k = (bid - CAST_BLKS - 64) * 4 + (t >> 6);
        const int l = t & 63;
        float4 wv = *(const float4*)&W_gat[(size_t)k * DM + 4 * l];
        float4 a1 = *(const float4*)&a_gat[4 * l];
        float4 a2 = *(const float4*)&a_gat[DM + 4 * l];
        float s1 = wv.x*a1.x + wv.y*a1.y + wv.z*a1.z + wv.w*a1.w;
        float s2 = wv.x*a2.x + wv.y*a2.y + wv.z*a2.z + wv.w*a2.w;
        #pragma unroll
        for (int off = 32; off; off >>= 1) {
            s1 += __shfl_xor(s1, off, 64);
            s2 += __shfl_xor(s2, off, 64);
        }
        if (l == 0) { w1[k] = s1; w2[k] = s2; }
    }
}

// ---------------- f1/f2: wave-per-row, float4 loads ----------------
__global__ __launch_bounds__(256) void f12_k(const float* __restrict__ src,
                                             const float* __restrict__ w1,
                                             const float* __restrict__ w2,
                                             float* __restrict__ f1,
                                             float* __restrict__ f2)
{
    const size_t row = (size_t)blockIdx.x * 4 + (threadIdx.x >> 6);
    const int l = threadIdx.x & 63;
    float4 sv = *(const float4*)&src[row * DM + 4 * l];
    float4 v1 = *(const float4*)&w1[4 * l];
    float4 v2 = *(const float4*)&w2[4 * l];
    float s1 = sv.x*v1.x + sv.y*v1.y + sv.z*v1.z + sv.w*v1.w;
    float s2 = sv.x*v2.x + sv.y*v2.y + sv.z*v2.z + sv.w*v2.w;
    #pragma unroll
    for (int off = 32; off; off >>= 1) {
        s1 += __shfl_xor(s1, off, 64);
        s2 += __shfl_xor(s2, off, 64);
    }
    if (l == 0) { f1[row] = s1 * LOG2E; f2[row] = s2 * LOG2E; }
}

// ---------------- bf16 MFMA GEMM: reg-prefetch + dbuf LDS, bf16 out ----------------
// EP: 1 +bias, 2 +bias,relu, 3 elu, 5 plain, 6 qkv(+bias, Q-scaled)
template<int EP, int BM, int BN>
__global__ __launch_bounds__(256) void gemm_bf(const ushort* __restrict__ A,
                                               const ushort* __restrict__ B,
                                               const float* __restrict__ bias,
                                               ushort* __restrict__ Cb,
                                               int N, int K, int ldB,
                                               long long sA, long long sB, long long sC)
{
    __shared__ ushort As[2][BM][40];
    __shared__ ushort Bs[2][BN][40];
    A += (size_t)blockIdx.z * sA;
    B += (size_t)blockIdx.z * sB;

    const int t  = threadIdx.x;
    const int m0 = blockIdx.y * BM, n0 = blockIdx.x * BN;
    const int lane = t & 63, lo = lane & 15, hi = lane >> 4;
    const int w = t >> 6;
    constexpr int NI = BM / 32, NJ = BN / 32;
    const int wr = (w >> 1) * (BM / 2);
    const int wc = (w & 1) * (BN / 2);

    const int lrA = (BM == 128) ? (t >> 1) : (t >> 2);
    const int lcA = (BM == 128) ? ((t & 1) * 16) : ((t & 3) * 8);
    const int lrB = (BN == 128) ? (t >> 1) : (t >> 2);
    const int lcB = (BN == 128) ? ((t & 1) * 16) : ((t & 3) * 8);

    f32x4 acc[NI][NJ];
    const f32x4 zero = {0.f, 0.f, 0.f, 0.f};
    #pragma unroll
    for (int i = 0; i < NI; i++)
        #pragma unroll
        for (int j = 0; j < NJ; j++) acc[i][j] = zero;

    const ushort* Ap = A + (size_t)(m0 + lrA) * K + lcA;
    const ushort* Bp = B + (size_t)(n0 + lrB) * ldB + lcB;

    short8 ar0, ar1, br0, br1;
    ar0 = *(const short8*)(Ap);
    if constexpr (BM == 128) ar1 = *(const short8*)(Ap + 8);
    br0 = *(const short8*)(Bp);
    if constexpr (BN == 128) br1 = *(const short8*)(Bp + 8);
    *(short8*)&As[0][lrA][lcA] = ar0;
    if constexpr (BM == 128) *(short8*)&As[0][lrA][lcA + 8] = ar1;
    *(short8*)&Bs[0][lrB][lcB] = br0;
    if constexpr (BN == 128) *(short8*)&Bs[0][lrB][lcB + 8] = br1;

    const int NT = K >> 5;
    for (int it = 0; it < NT; it++) {
        const int cur = it & 1;
        if (it + 1 < NT) {
            const int k0 = (it + 1) << 5;
            ar0 = *(const short8*)(Ap + k0);
            if constexpr (BM == 128) ar1 = *(const short8*)(Ap + k0 + 8);
            br0 = *(const short8*)(Bp + k0);
            if constexpr (BN == 128) br1 = *(const short8*)(Bp + k0 + 8);
        }
        __syncthreads();

        short8 afr[NI], bfr[NJ];
        #pragma unroll
        for (int i = 0; i < NI; i++) afr[i] = *(const short8*)&As[cur][wr + i*16 + lo][hi * 8];
        #pragma unroll
        for (int j = 0; j < NJ; j++) bfr[j] = *(const short8*)&Bs[cur][wc + j*16 + lo][hi * 8];
        #pragma unroll
        for (int i = 0; i < NI; i++)
            #pragma unroll
            for (int j = 0; j < NJ; j++)
                acc[i][j] = __builtin_amdgcn_mfma_f32_16x16x32_bf16(afr[i], bfr[j], acc[i][j], 0, 0, 0);

        if (it + 1 < NT) {
            *(short8*)&As[cur ^ 1][lrA][lcA] = ar0;
            if constexpr (BM == 128) *(short8*)&As[cur ^ 1][lrA][lcA + 8] = ar1;
            *(short8*)&Bs[cur ^ 1][lrB][lcB] = br0;
            if constexpr (BN == 128) *(short8*)&Bs[cur ^ 1][lrB][lcB + 8] = br1;
        }
    }

    Cb += (size_t)blockIdx.z * sC;
    #pragma unroll
    for (int j = 0; j < NJ; j++) {
        const int col = n0 + wc + j * 16 + lo;
        float bj = (EP == 1 || EP == 2 || EP == 6) ? bias[col] : 0.f;
        #pragma unroll
        for (int i = 0; i < NI; i++) {
            const int rbase = m0 + wr + i * 16 + hi * 4;
            #pragma unroll
            for (int r = 0; r < 4; r++) {
                float v = acc[i][j][r] + bj;
                if (EP == 3) v = v > 0.f ? v : expm1f(v);
                if (EP == 2) v = fmaxf(v, 0.f);
                if (EP == 6 && col < DM) v *= QSCALE;
                Cb[(size_t)(rbase + r) * N + col] = f2bf(v);
            }
        }
    }
}

// ---------------- LayerNorm(a + r)*g + b: wave-per-row ----------------
// MODE 0: a=f32, out=bf16; MODE 1: a=bf16, out=bf16; MODE 2: a=bf16, out=f32
template<int MODE>
__global__ __launch_bounds__(256) void ln_k(const float* __restrict__ af,
                                            const ushort* __restrict__ ab,
                                            const ushort* __restrict__ r,
                                            const float* __restrict__ g,
                                            const float* __restrict__ be,
                                            float* __restrict__ of,
                                            ushort* __restrict__ ob)
{
    const size_t row = (size_t)blockIdx.x * 4 + (threadIdx.x >> 6);
    const int l = threadIdx.x & 63;
    ushort4 rv = *(const ushort4*)&r[row * DM + 4 * l];
    float v0, v1, v2, v3;
    if (MODE == 0) {
        float4 av = *(const float4*)&af[row * DM + 4 * l];
        v0 = av.x + bf2f(rv.x); v1 = av.y + bf2f(rv.y);
        v2 = av.z + bf2f(rv.z); v3 = av.w + bf2f(rv.w);
    } else {
        ushort4 av = *(const ushort4*)&ab[row * DM + 4 * l];
        v0 = bf2f(av.x) + bf2f(rv.x); v1 = bf2f(av.y) + bf2f(rv.y);
        v2 = bf2f(av.z) + bf2f(rv.z); v3 = bf2f(av.w) + bf2f(rv.w);
    }
    float s = (v0 + v1) + (v2 + v3);
    #pragma unroll
    for (int off = 32; off; off >>= 1) s += __shfl_xor(s, off, 64);
    const float mu = s * (1.0f / DM);
    float q = (v0-mu)*(v0-mu) + (v1-mu)*(v1-mu) + (v2-mu)*(v2-mu) + (v3-mu)*(v3-mu);
    #pragma unroll
    for (int off = 32; off; off >>= 1) q += __shfl_xor(q, off, 64);
    const float rs = rsqrtf(q * (1.0f / DM) + EPSV);
    float4 gv = *(const float4*)&g[4 * l];
    float4 bv = *(const float4*)&be[4 * l];
    float o0 = (v0 - mu) * rs * gv.x + bv.x;
    float o1 = (v1 - mu) * rs * gv.y + bv.y;
    float o2 = (v2 - mu) * rs * gv.z + bv.z;
    float o3 = (v3 - mu) * rs * gv.w + bv.w;
    if (MODE == 2) {
        float4 ov; ov.x = o0; ov.y = o1; ov.z = o2; ov.w = o3;
        *(float4*)&of[row * DM + 4 * l] = ov;
    } else {
        ushort4 obv;
        obv.x = f2bf(o0); obv.y = f2bf(o1); obv.z = f2bf(o2); obv.w = f2bf(o3);
        *(ushort4*)&ob[row * DM + 4 * l] = obv;
    }
}

// ---------------- GAT masked softmax: wave-per-row, no barriers ----------------
__global__ __launch_bounds__(256) void gat_sm_k(const int* __restrict__ adj,
                                                const float* __restrict__ f1,
                                                const float* __restrict__ f2,
                                                ushort* __restrict__ P)
{
    const int row = blockIdx.x * 4 + (threadIdx.x >> 6);
    const int b = row >> 10;
    const int l = threadIdx.x & 63;
    const int* arow = adj + (size_t)row * SEQ;
    const float* f2b = f2 + ((size_t)b << 10);
    const float f1i = f1[row];

    float e[16];
    float mx = -3.4e38f;
    #pragma unroll
    for (int u = 0; u < 4; u++) {
        const int j = 4 * l + 256 * u;
        int4 a4 = *(const int4*)&arow[j];
        float4 f4 = *(const float4*)&f2b[j];
        e[4*u+0] = a4.x > 0 ? f1i + f4.x : NEGV;
        e[4*u+1] = a4.y > 0 ? f1i + f4.y : NEGV;
        e[4*u+2] = a4.z > 0 ? f1i + f4.z : NEGV;
        e[4*u+3] = a4.w > 0 ? f1i + f4.w : NEGV;
        mx = fmaxf(mx, fmaxf(fmaxf(e[4*u], e[4*u+1]), fmaxf(e[4*u+2], e[4*u+3])));
    }
    #pragma unroll
    for (int off = 32; off; off >>= 1) mx = fmaxf(mx, __shfl_xor(mx, off, 64));
    float s = 0.f;
    #pragma unroll
    for (int k = 0; k < 16; k++) { e[k] = exp2f(e[k] - mx); s += e[k]; }
    #pragma unroll
    for (int off = 32; off; off >>= 1) s += __shfl_xor(s, off, 64);
    const float inv = 1.0f / s;
    #pragma unroll
    for (int u = 0; u < 4; u++) {
        ushort4 o;
        o.x = f2bf(e[4*u+0] * inv); o.y = f2bf(e[4*u+1] * inv);
        o.z = f2bf(e[4*u+2] * inv); o.w = f2bf(e[4*u+3] * inv);
        *(ushort4*)&P[(size_t)row * SEQ + 4 * l + 256 * u] = o;
    }
}

// ---------------- MHA v6: 128 q-rows / block, 8 waves, split K/V staging ----------------
__device__ __forceinline__ int vt_idx(int d, int kv) { return d * 72 + ((d >> 3) & 3) * 16 + kv; }
constexpr int VTSZ = 32 * 72 + 3 * 16 + 8;

__global__ __launch_bounds__(512) void mha_k(const ushort* __restrict__ qkv,
                                             ushort* __restrict__ ctxb)
{
    __shared__ ushort Ks[2][64][40];
    __shared__ ushort Vt[2][VTSZ];
    __shared__ ushort Ps[128][72];

    const int blk = blockIdx.x;
    const int grp = blk & 63, qt = blk >> 6;
    const int h = grp & 7, b = grp >> 3;
    const int i0 = qt << 7;
    const int t = threadIdx.x;
    const int w = t >> 6, lane = t & 63, lo = lane & 15, hi = lane >> 4;
    const int gsh = lane & 48;
    const size_t base = (size_t)b * SEQ * 768;

    const short8 aQ = *(const short8*)(qkv + base + (size_t)(i0 + 16*w + lo) * 768 + h * HDIM + hi * 8);
    short8 ones;
    #pragma unroll
    for (int e = 0; e < 8; e++) ones[e] = (short)0x3F80;

    const int tt = t & 255;
    const int srow = tt >> 2, scb = (tt & 3) << 3;
    const bool isK = t < 256;
    const int vcol = (srow & 32) | ((srow & 15) << 1) | ((srow >> 4) & 1);
    {
        const ushort* p0 = qkv + base + (size_t)srow * 768 + h * HDIM + (isK ? 256 : 512) + scb;
        short8 v0 = *(const short8*)p0;
        if (isK) *(short8*)&Ks[0][srow][scb] = v0;
        else {
            #pragma unroll
            for (int e = 0; e < 8; e++) Vt[0][vt_idx(scb + e, vcol)] = (ushort)v0[e];
        }
    }

    float m_run[4], l_run[4];
    f32x4 O0 = {0.f, 0.f, 0.f, 0.f}, O1 = {0.f, 0.f, 0.f, 0.f};
    #pragma unroll
    for (int r = 0; r < 4; r++) { m_run[r] = -3.0e38f; l_run[r] = 0.f; }
    const f32x4 zero = {0.f, 0.f, 0.f, 0.f};

    short8 reg;
    for (int it = 0; it < 16; it++) {
        const int cur = it & 1;
        if (it < 15)
            reg = *(const short8*)(qkv + base + (size_t)((it + 1) * 64 + srow) * 768
                                   + h * HDIM + (isK ? 256 : 512) + scb);
        __syncthreads();

        f32x4 S[4];
        #pragma unroll
        for (int jt = 0; jt < 4; jt++) {
            short8 bK = *(const short8*)&Ks[cur][16 * jt + lo][hi * 8];
            S[jt] = __builtin_amdgcn_mfma_f32_16x16x32_bf16(aQ, bK, zero, 0, 0, 0);
        }

        float mxl[4];
        bool any = false;
        #pragma unroll
        for (int r = 0; r < 4; r++) {
            mxl[r] = fmaxf(fmaxf(S[0][r], S[1][r]), fmaxf(S[2][r], S[3][r]));
            any = any || (mxl[r] > m_run[r] + 8.f);
        }
        unsigned long long bal = __ballot(any);
        if ((bal >> gsh) & 0xffffULL) {
            #pragma unroll
            for (int r = 0; r < 4; r++) {
                float mx = mxl[r];
                #pragma unroll
                for (int off = 8; off; off >>= 1) mx = fmaxf(mx, __shfl_xor(mx, off, 16));
                float mnew = fmaxf(m_run[r], mx);
                float sc = exp2f(m_run[r] - mnew);
                m_run[r] = mnew;
                l_run[r] *= sc; O0[r] *= sc; O1[r] *= sc;
            }
        }
        #pragma unroll
        for (int r = 0; r < 4; r++) {
            const int row = 16 * w + 4 * hi + r;
            unsigned u01 = cvt_pk_bf16(exp2f(S[0][r] - m_run[r]), exp2f(S[1][r] - m_run[r]));
            unsigned u23 = cvt_pk_bf16(exp2f(S[2][r] - m_run[r]), exp2f(S[3][r] - m_run[r]));
            *(unsigned*)&Ps[row][2 * lo]      = u01;
            *(unsigned*)&Ps[row][32 + 2 * lo] = u23;
        }

        f32x4 O2 = zero;
        #pragma unroll
        for (int kt = 0; kt < 2; kt++) {
            short8 aP  = *(const short8*)&Ps[16 * w + lo][32 * kt + hi * 8];
            short8 bV0 = *(const short8*)&Vt[cur][vt_idx(lo,      32 * kt + hi * 8)];
            short8 bV1 = *(const short8*)&Vt[cur][vt_idx(16 + lo, 32 * kt + hi * 8)];
            O0 = __builtin_amdgcn_mfma_f32_16x16x32_bf16(aP, bV0, O0, 0, 0, 0);
            O1 = __builtin_amdgcn_mfma_f32_16x16x32_bf16(aP, bV1, O1, 0, 0, 0);
            O2 = __builtin_amdgcn_mfma_f32_16x16x32_bf16(aP, ones, O2, 0, 0, 0);
        }
        #pragma unroll
        for (int r = 0; r < 4; r++) l_run[r] += O2[r];

        if (it < 15) {
            if (isK) *(short8*)&Ks[cur ^ 1][srow][scb] = reg;
            else {
                #pragma unroll
                for (int e = 0; e < 8; e++) Vt[cur ^ 1][vt_idx(scb + e, vcol)] = (ushort)reg[e];
            }
        }
    }

    #pragma unroll
    for (int r = 0; r < 4; r++) {
        float inv = 1.0f / l_run[r];
        size_t row = (size_t)b * SEQ + i0 + 16 * w + 4 * hi + r;
        ctxb[row * DM + h * HDIM + lo]      = f2bf(O0[r] * inv);
        ctxb[row * DM + h * HDIM + 16 + lo] = f2bf(O1[r] * inv);
    }
}

extern "C" void kernel_launch(void* const* d_in, const int* in_sizes, int n_in,
                              void* d_out, int out_size, void* d_ws, size_t ws_size,
                              hipStream_t stream)
{
    const float* src        = (const float*)d_in[0];
    const int*   adj        = (const int*)  d_in[1];
    const float* W_gat      = (const float*)d_in[2];
    const float* a_gat      = (const float*)d_in[3];
    const float* in_proj_w  = (const float*)d_in[4];
    const float* in_proj_b  = (const float*)d_in[5];
    const float* out_proj_w = (const float*)d_in[6];
    const float* out_proj_b = (const float*)d_in[7];
    const float* lin1_w     = (const float*)d_in[8];
    const float* lin1_b     = (const float*)d_in[9];
    const float* lin2_w     = (const float*)d_in[10];
    const float* lin2_b     = (const float*)d_in[11];
    const float* ln1_g      = (const float*)d_in[12];
    const float* ln1_b_     = (const float*)d_in[13];
    const float* ln2_g      = (const float*)d_in[14];
    const float* ln2_b_     = (const float*)d_in[15];
    const float* ln3_g      = (const float*)d_in[16];
    const float* ln3_b_     = (const float*)d_in[17];

    char* base = (char*)d_ws;
    const size_t MB = 1024 * 1024;
    ushort* tmpb  = (ushort*)(base + 0 * MB);    // 4 MB (bf16 pre-LN GEMM out)
    ushort* P_bf  = (ushort*)(base + 4 * MB);    // 16 MB (then qkvb / ff1b)
    ushort* qkvb  = (ushort*)(base + 4 * MB);
    ushort* ff1b  = (ushort*)(base + 4 * MB);
    ushort* srcb  = (ushort*)(base + 36 * MB);   // 4 MB
    ushort* WhTb  = (ushort*)(base + 40 * MB);   // 4 MB ([256][8192])
    ushort* xb    = (ushort*)(base + 44 * MB);   // 4 MB
    ushort* yb    = (ushort*)(base + 48 * MB);   // 4 MB
    ushort* ctxb  = (ushort*)(base + 52 * MB);   // 4 MB
    float*  f1    = (float*) (base + 56 * MB);
    float*  f2    = f1 + ROWS;
    float*  w1    = f2 + ROWS;
    float*  w2    = w1 + DM;
    ushort* wgTb  = (ushort*)(base + 57 * MB);
    ushort* ipwb  = wgTb + 65536;
    ushort* opwb  = ipwb + 196608;
    ushort* l1wb  = opwb + 65536;
    ushort* l2wb  = l1wb + 524288;

    dim3 b256(256);

    CastArgs ca;
    ca.in[0] = src;       ca.out[0] = srcb; ca.n4[0] = 2097152 / 4;
    ca.in[1] = in_proj_w; ca.out[1] = ipwb; ca.n4[1] = 196608 / 4;
    ca.in[2] = out_proj_w;ca.out[2] = opwb; ca.n4[2] = 65536 / 4;
    ca.in[3] = lin1_w;    ca.out[3] = l1wb; ca.n4[3] = 524288 / 4;
    ca.in[4] = lin2_w;    ca.out[4] = l2wb; ca.n4[4] = 524288 / 4;
    prep_k<<<CAST_BLKS + 64 + 64, b256, 0, stream>>>(ca, W_gat, a_gat, wgTb, w1, w2);

    // --- GAT ---
    f12_k<<<ROWS / 4, b256, 0, stream>>>(src, w1, w2, f1, f2);
    gemm_bf<5, 64, 64><<<dim3(ROWS/64, DM/64, 1), b256, 0, stream>>>(wgTb, srcb, nullptr, WhTb,
                                                                     ROWS, DM, DM, 0, 0, 0);
    gat_sm_k<<<ROWS / 4, b256, 0, stream>>>(adj, f1, f2, P_bf);
    gemm_bf<3, 64, 64><<<dim3(DM/64, SEQ/64, 8), b256, 0, stream>>>(P_bf, WhTb, nullptr, tmpb,
                                                                    DM, SEQ, ROWS,
                                                                    (long long)SEQ * SEQ, (long long)SEQ, (long long)SEQ * DM);
    ln_k<0><<<ROWS / 4, b256, 0, stream>>>(src, nullptr, tmpb, ln1_g, ln1_b_, nullptr, xb);

    // --- MHA ---
    gemm_bf<6, 128, 64><<<dim3(768/64, ROWS/128, 1), b256, 0, stream>>>(xb, ipwb, in_proj_b, qkvb,
                                                                        768, DM, DM, 0, 0, 0);
    mha_k<<<BATCH * NH * (SEQ / 128), dim3(512), 0, stream>>>(qkvb, ctxb);
    gemm_bf<1, 64, 64><<<dim3(DM/64, ROWS/64, 1), b256, 0, stream>>>(ctxb, opwb, out_proj_b, tmpb,
                                                                     DM, DM, DM, 0, 0, 0);
    ln_k<1><<<ROWS / 4, b256, 0, stream>>>(nullptr, xb, tmpb, ln2_g, ln2_b_, nullptr, yb);

    // --- FFN ---
    gemm_bf<2, 128, 128><<<dim3(DF/128, ROWS/128, 1), b256, 0, stream>>>(yb, l1wb, lin1_b, ff1b,
                                                                         DF, DM, DM, 0, 0, 0);
    gemm_bf<1, 64, 64><<<dim3(DM/64, ROWS/64, 1), b256, 0, stream>>>(ff1b, l2wb, lin2_b, tmpb,
                                                                     DM, DF, DF, 0, 0, 0);
    ln_k<2><<<ROWS / 4, b256, 0, stream>>>(nullptr, yb, tmpb, ln3_g, ln3_b_, (float*)d_out, nullptr);
}

// Round 16
// 153.314 us; speedup vs baseline: 1.0636x; 1.0153x over previous
//
#include <hip/hip_runtime.h>
#include <math.h>

constexpr int BATCH = 8;
constexpr int SEQ   = 1024;
constexpr int DM    = 256;
constexpr int DF    = 2048;
constexpr int NH    = 8;
constexpr int HDIM  = 32;
constexpr int ROWS  = BATCH * SEQ;    // 8192
constexpr float NEGV = -9e15f;
constexpr float EPSV = 1e-5f;
constexpr float QSCALE = 0.2550351822f;   // 1/sqrt(32) * log2(e)
constexpr float LOG2E  = 1.44269504f;

typedef __attribute__((ext_vector_type(8))) short short8;
typedef __attribute__((ext_vector_type(4))) float f32x4;

static __device__ __forceinline__ ushort f2bf(float f) {
    unsigned x = __float_as_uint(f);
    unsigned r = (x + 0x7fffu + ((x >> 16) & 1u)) >> 16;   // RNE
    return (ushort)r;
}
static __device__ __forceinline__ float bf2f(ushort u) {
    return __uint_as_float((unsigned)u << 16);
}
static __device__ __forceinline__ unsigned cvt_pk_bf16(float lo, float hi) {
    unsigned r;
    asm volatile("v_cvt_pk_bf16_f32 %0, %1, %2" : "=v"(r) : "v"(lo), "v"(hi));
    return r;
}

// ---------------- fused prep: 5-region cast + W_gat transpose-cast + w12 ----------------
struct CastArgs {
    const float* in[5];
    ushort* out[5];
    int n4[5];
};
constexpr int CAST_BLKS = (2097152 + 196608 + 65536 + 524288 + 524288) / 4 / 256;  // 3328

__global__ __launch_bounds__(256) void prep_k(CastArgs a,
                                              const float* __restrict__ W_gat,
                                              const float* __restrict__ a_gat,
                                              ushort* __restrict__ wgTb,
                                              float* __restrict__ w1,
                                              float* __restrict__ w2)
{
    __shared__ float Ts[32][33];
    const int bid = blockIdx.x;
    const int t = threadIdx.x;

    if (bid < CAST_BLKS) {
        int idx = bid * 256 + t;
        #pragma unroll
        for (int r = 0; r < 5; r++) {
            if (idx < a.n4[r]) {
                float4 v = *(const float4*)&a.in[r][(size_t)idx * 4];
                ushort4 o; o.x = f2bf(v.x); o.y = f2bf(v.y); o.z = f2bf(v.z); o.w = f2bf(v.w);
                *(ushort4*)&a.out[r][(size_t)idx * 4] = o;
                return;
            }
            idx -= a.n4[r];
        }
    } else if (bid < CAST_BLKS + 64) {
        const int bb = bid - CAST_BLKS;
        const int r0 = (bb >> 3) * 32, c0 = (bb & 7) * 32;
        const int lr = t >> 3, lc4 = (t & 7) * 4;
        float4 v = *(const float4*)&W_gat[(size_t)(r0 + lr) * DM + c0 + lc4];
        Ts[lr][lc4] = v.x; Ts[lr][lc4 + 1] = v.y; Ts[lr][lc4 + 2] = v.z; Ts[lr][lc4 + 3] = v.w;
        __syncthreads();
        const int oc = t >> 3, or4 = (t & 7) * 4;
        ushort4 o;
        o.x = f2bf(Ts[or4 + 0][oc]); o.y = f2bf(Ts[or4 + 1][oc]);
        o.z = f2bf(Ts[or4 + 2][oc]); o.w = f2bf(Ts[or4 + 3][oc]);
        *(ushort4*)&wgTb[(size_t)(c0 + oc) * DM + r0 + or4] = o;
    } else {
        const int k = (bid - CAST_BLKS - 64) * 4 + (t >> 6);
        const int l = t & 63;
        float4 wv = *(const float4*)&W_gat[(size_t)k * DM + 4 * l];
        float4 a1 = *(const float4*)&a_gat[4 * l];
        float4 a2 = *(const float4*)&a_gat[DM + 4 * l];
        float s1 = wv.x*a1.x + wv.y*a1.y + wv.z*a1.z + wv.w*a1.w;
        float s2 = wv.x*a2.x + wv.y*a2.y + wv.z*a2.z + wv.w*a2.w;
        #pragma unroll
        for (int off = 32; off; off >>= 1) {
            s1 += __shfl_xor(s1, off, 64);
            s2 += __shfl_xor(s2, off, 64);
        }
        if (l == 0) { w1[k] = s1; w2[k] = s2; }
    }
}

// ---------------- fused: WhT GEMM (blocks 0..511) + f1/f2 (blocks 512..2559) ----------------
// Independent workloads; GEMM blocks first so the long work starts immediately.
__global__ __launch_bounds__(256) void fwt_k(const ushort* __restrict__ Awg,   // wgTb (DM x DM)
                                             const ushort* __restrict__ Bsrc,  // srcb (ROWS x DM)
                                             ushort* __restrict__ WhT,         // out [DM][ROWS]
                                             const float* __restrict__ src,
                                             const float* __restrict__ w1,
                                             const float* __restrict__ w2,
                                             float* __restrict__ f1,
                                             float* __restrict__ f2)
{
    __shared__ ushort As[2][64][40];
    __shared__ ushort Bs[2][64][40];
    const int bid = blockIdx.x;
    const int t = threadIdx.x;

    if (bid >= 512) {   // ---- f12: wave-per-row ----
        const size_t row = (size_t)(bid - 512) * 4 + (t >> 6);
        const int l = t & 63;
        float4 sv = *(const float4*)&src[row * DM + 4 * l];
        float4 v1 = *(const float4*)&w1[4 * l];
        float4 v2 = *(const float4*)&w2[4 * l];
        float s1 = sv.x*v1.x + sv.y*v1.y + sv.z*v1.z + sv.w*v1.w;
        float s2 = sv.x*v2.x + sv.y*v2.y + sv.z*v2.z + sv.w*v2.w;
        #pragma unroll
        for (int off = 32; off; off >>= 1) {
            s1 += __shfl_xor(s1, off, 64);
            s2 += __shfl_xor(s2, off, 64);
        }
        if (l == 0) { f1[row] = s1 * LOG2E; f2[row] = s2 * LOG2E; }
        return;
    }

    // ---- WhT = wgTb @ srcb^T, BM=BN=64, EP=5 (plain bf16 out) ----
    const int m0 = (bid >> 7) * 64, n0 = (bid & 127) * 64;   // M=DM (4 tiles), N=ROWS (128 tiles)
    const int lane = t & 63, lo = lane & 15, hi = lane >> 4;
    const int w = t >> 6;
    const int wr = (w >> 1) * 32, wc = (w & 1) * 32;

    const int lrA = t >> 2, lcA = (t & 3) * 8;
    const int lrB = t >> 2, lcB = (t & 3) * 8;

    f32x4 acc[2][2];
    const f32x4 zero = {0.f, 0.f, 0.f, 0.f};
    #pragma unroll
    for (int i = 0; i < 2; i++)
        #pragma unroll
        for (int j = 0; j < 2; j++) acc[i][j] = zero;

    const ushort* Ap = Awg + (size_t)(m0 + lrA) * DM + lcA;
    const ushort* Bp = Bsrc + (size_t)(n0 + lrB) * DM + lcB;

    short8 ar0 = *(const short8*)(Ap);
    short8 br0 = *(const short8*)(Bp);
    *(short8*)&As[0][lrA][lcA] = ar0;
    *(short8*)&Bs[0][lrB][lcB] = br0;

    const int NT = DM >> 5;
    for (int it = 0; it < NT; it++) {
        const int cur = it & 1;
        if (it + 1 < NT) {
            const int k0 = (it + 1) << 5;
            ar0 = *(const short8*)(Ap + k0);
            br0 = *(const short8*)(Bp + k0);
        }
        __syncthreads();

        short8 afr[2], bfr[2];
        #pragma unroll
        for (int i = 0; i < 2; i++) afr[i] = *(const short8*)&As[cur][wr + i*16 + lo][hi * 8];
        #pragma unroll
        for (int j = 0; j < 2; j++) bfr[j] = *(const short8*)&Bs[cur][wc + j*16 + lo][hi * 8];
        #pragma unroll
        for (int i = 0; i < 2; i++)
            #pragma unroll
            for (int j = 0; j < 2; j++)
                acc[i][j] = __builtin_amdgcn_mfma_f32_16x16x32_bf16(afr[i], bfr[j], acc[i][j], 0, 0, 0);

        if (it + 1 < NT) {
            *(short8*)&As[cur ^ 1][lrA][lcA] = ar0;
            *(short8*)&Bs[cur ^ 1][lrB][lcB] = br0;
        }
    }

    #pragma unroll
    for (int j = 0; j < 2; j++) {
        const int col = n0 + wc + j * 16 + lo;
        #pragma unroll
        for (int i = 0; i < 2; i++) {
            const int rbase = m0 + wr + i * 16 + hi * 4;
            #pragma unroll
            for (int r = 0; r < 4; r++)
                WhT[(size_t)(rbase + r) * ROWS + col] = f2bf(acc[i][j][r]);
        }
    }
}

// ---------------- bf16 MFMA GEMM: reg-prefetch + dbuf LDS, bf16 out ----------------
// EP: 1 +bias, 2 +bias,relu, 3 elu, 5 plain, 6 qkv(+bias, Q-scaled)
template<int EP, int BM, int BN>
__global__ __launch_bounds__(256) void gemm_bf(const ushort* __restrict__ A,
                                               const ushort* __restrict__ B,
                                               const float* __restrict__ bias,
                                               ushort* __restrict__ Cb,
                                               int N, int K, int ldB,
                                               long long sA, long long sB, long long sC)
{
    __shared__ ushort As[2][BM][40];
    __shared__ ushort Bs[2][BN][40];
    A += (size_t)blockIdx.z * sA;
    B += (size_t)blockIdx.z * sB;

    const int t  = threadIdx.x;
    const int m0 = blockIdx.y * BM, n0 = blockIdx.x * BN;
    const int lane = t & 63, lo = lane & 15, hi = lane >> 4;
    const int w = t >> 6;
    constexpr int NI = BM / 32, NJ = BN / 32;
    const int wr = (w >> 1) * (BM / 2);
    const int wc = (w & 1) * (BN / 2);

    const int lrA = (BM == 128) ? (t >> 1) : (t >> 2);
    const int lcA = (BM == 128) ? ((t & 1) * 16) : ((t & 3) * 8);
    const int lrB = (BN == 128) ? (t >> 1) : (t >> 2);
    const int lcB = (BN == 128) ? ((t & 1) * 16) : ((t & 3) * 8);

    f32x4 acc[NI][NJ];
    const f32x4 zero = {0.f, 0.f, 0.f, 0.f};
    #pragma unroll
    for (int i = 0; i < NI; i++)
        #pragma unroll
        for (int j = 0; j < NJ; j++) acc[i][j] = zero;

    const ushort* Ap = A + (size_t)(m0 + lrA) * K + lcA;
    const ushort* Bp = B + (size_t)(n0 + lrB) * ldB + lcB;

    short8 ar0, ar1, br0, br1;
    ar0 = *(const short8*)(Ap);
    if constexpr (BM == 128) ar1 = *(const short8*)(Ap + 8);
    br0 = *(const short8*)(Bp);
    if constexpr (BN == 128) br1 = *(const short8*)(Bp + 8);
    *(short8*)&As[0][lrA][lcA] = ar0;
    if constexpr (BM == 128) *(short8*)&As[0][lrA][lcA + 8] = ar1;
    *(short8*)&Bs[0][lrB][lcB] = br0;
    if constexpr (BN == 128) *(short8*)&Bs[0][lrB][lcB + 8] = br1;

    const int NT = K >> 5;
    for (int it = 0; it < NT; it++) {
        const int cur = it & 1;
        if (it + 1 < NT) {
            const int k0 = (it + 1) << 5;
            ar0 = *(const short8*)(Ap + k0);
            if constexpr (BM == 128) ar1 = *(const short8*)(Ap + k0 + 8);
            br0 = *(const short8*)(Bp + k0);
            if constexpr (BN == 128) br1 = *(const short8*)(Bp + k0 + 8);
        }
        __syncthreads();

        short8 afr[NI], bfr[NJ];
        #pragma unroll
        for (int i = 0; i < NI; i++) afr[i] = *(const short8*)&As[cur][wr + i*16 + lo][hi * 8];
        #pragma unroll
        for (int j = 0; j < NJ; j++) bfr[j] = *(const short8*)&Bs[cur][wc + j*16 + lo][hi * 8];
        #pragma unroll
        for (int i = 0; i < NI; i++)
            #pragma unroll
            for (int j = 0; j < NJ; j++)
                acc[i][j] = __builtin_amdgcn_mfma_f32_16x16x32_bf16(afr[i], bfr[j], acc[i][j], 0, 0, 0);

        if (it + 1 < NT) {
            *(short8*)&As[cur ^ 1][lrA][lcA] = ar0;
            if constexpr (BM == 128) *(short8*)&As[cur ^ 1][lrA][lcA + 8] = ar1;
            *(short8*)&Bs[cur ^ 1][lrB][lcB] = br0;
            if constexpr (BN == 128) *(short8*)&Bs[cur ^ 1][lrB][lcB + 8] = br1;
        }
    }

    Cb += (size_t)blockIdx.z * sC;
    #pragma unroll
    for (int j = 0; j < NJ; j++) {
        const int col = n0 + wc + j * 16 + lo;
        float bj = (EP == 1 || EP == 2 || EP == 6) ? bias[col] : 0.f;
        #pragma unroll
        for (int i = 0; i < NI; i++) {
            const int rbase = m0 + wr + i * 16 + hi * 4;
            #pragma unroll
            for (int r = 0; r < 4; r++) {
                float v = acc[i][j][r] + bj;
                if (EP == 3) v = v > 0.f ? v : expm1f(v);
                if (EP == 2) v = fmaxf(v, 0.f);
                if (EP == 6 && col < DM) v *= QSCALE;
                Cb[(size_t)(rbase + r) * N + col] = f2bf(v);
            }
        }
    }
}

// ---------------- LayerNorm(a + r)*g + b: wave-per-row ----------------
// MODE 0: a=f32, out=bf16; MODE 1: a=bf16, out=bf16; MODE 2: a=bf16, out=f32
template<int MODE>
__global__ __launch_bounds__(256) void ln_k(const float* __restrict__ af,
                                            const ushort* __restrict__ ab,
                                            const ushort* __restrict__ r,
                                            const float* __restrict__ g,
                                            const float* __restrict__ be,
                                            float* __restrict__ of,
                                            ushort* __restrict__ ob)
{
    const size_t row = (size_t)blockIdx.x * 4 + (threadIdx.x >> 6);
    const int l = threadIdx.x & 63;
    ushort4 rv = *(const ushort4*)&r[row * DM + 4 * l];
    float v0, v1, v2, v3;
    if (MODE == 0) {
        float4 av = *(const float4*)&af[row * DM + 4 * l];
        v0 = av.x + bf2f(rv.x); v1 = av.y + bf2f(rv.y);
        v2 = av.z + bf2f(rv.z); v3 = av.w + bf2f(rv.w);
    } else {
        ushort4 av = *(const ushort4*)&ab[row * DM + 4 * l];
        v0 = bf2f(av.x) + bf2f(rv.x); v1 = bf2f(av.y) + bf2f(rv.y);
        v2 = bf2f(av.z) + bf2f(rv.z); v3 = bf2f(av.w) + bf2f(rv.w);
    }
    float s = (v0 + v1) + (v2 + v3);
    #pragma unroll
    for (int off = 32; off; off >>= 1) s += __shfl_xor(s, off, 64);
    const float mu = s * (1.0f / DM);
    float q = (v0-mu)*(v0-mu) + (v1-mu)*(v1-mu) + (v2-mu)*(v2-mu) + (v3-mu)*(v3-mu);
    #pragma unroll
    for (int off = 32; off; off >>= 1) q += __shfl_xor(q, off, 64);
    const float rs = rsqrtf(q * (1.0f / DM) + EPSV);
    float4 gv = *(const float4*)&g[4 * l];
    float4 bv = *(const float4*)&be[4 * l];
    float o0 = (v0 - mu) * rs * gv.x + bv.x;
    float o1 = (v1 - mu) * rs * gv.y + bv.y;
    float o2 = (v2 - mu) * rs * gv.z + bv.z;
    float o3 = (v3 - mu) * rs * gv.w + bv.w;
    if (MODE == 2) {
        float4 ov; ov.x = o0; ov.y = o1; ov.z = o2; ov.w = o3;
        *(float4*)&of[row * DM + 4 * l] = ov;
    } else {
        ushort4 obv;
        obv.x = f2bf(o0); obv.y = f2bf(o1); obv.z = f2bf(o2); obv.w = f2bf(o3);
        *(ushort4*)&ob[row * DM + 4 * l] = obv;
    }
}

// ---------------- GAT masked softmax: wave-per-row, no barriers ----------------
__global__ __launch_bounds__(256) void gat_sm_k(const int* __restrict__ adj,
                                                const float* __restrict__ f1,
                                                const float* __restrict__ f2,
                                                ushort* __restrict__ P)
{
    const int row = blockIdx.x * 4 + (threadIdx.x >> 6);
    const int b = row >> 10;
    const int l = threadIdx.x & 63;
    const int* arow = adj + (size_t)row * SEQ;
    const float* f2b = f2 + ((size_t)b << 10);
    const float f1i = f1[row];

    float e[16];
    float mx = -3.4e38f;
    #pragma unroll
    for (int u = 0; u < 4; u++) {
        const int j = 4 * l + 256 * u;
        int4 a4 = *(const int4*)&arow[j];
        float4 f4 = *(const float4*)&f2b[j];
        e[4*u+0] = a4.x > 0 ? f1i + f4.x : NEGV;
        e[4*u+1] = a4.y > 0 ? f1i + f4.y : NEGV;
        e[4*u+2] = a4.z > 0 ? f1i + f4.z : NEGV;
        e[4*u+3] = a4.w > 0 ? f1i + f4.w : NEGV;
        mx = fmaxf(mx, fmaxf(fmaxf(e[4*u], e[4*u+1]), fmaxf(e[4*u+2], e[4*u+3])));
    }
    #pragma unroll
    for (int off = 32; off; off >>= 1) mx = fmaxf(mx, __shfl_xor(mx, off, 64));
    float s = 0.f;
    #pragma unroll
    for (int k = 0; k < 16; k++) { e[k] = exp2f(e[k] - mx); s += e[k]; }
    #pragma unroll
    for (int off = 32; off; off >>= 1) s += __shfl_xor(s, off, 64);
    const float inv = 1.0f / s;
    #pragma unroll
    for (int u = 0; u < 4; u++) {
        ushort4 o;
        o.x = f2bf(e[4*u+0] * inv); o.y = f2bf(e[4*u+1] * inv);
        o.z = f2bf(e[4*u+2] * inv); o.w = f2bf(e[4*u+3] * inv);
        *(ushort4*)&P[(size_t)row * SEQ + 4 * l + 256 * u] = o;
    }
}

// ---------------- MHA v6: 128 q-rows / block, 8 waves, split K/V staging ----------------
__device__ __forceinline__ int vt_idx(int d, int kv) { return d * 72 + ((d >> 3) & 3) * 16 + kv; }
constexpr int VTSZ = 32 * 72 + 3 * 16 + 8;

__global__ __launch_bounds__(512) void mha_k(const ushort* __restrict__ qkv,
                                             ushort* __restrict__ ctxb)
{
    __shared__ ushort Ks[2][64][40];
    __shared__ ushort Vt[2][VTSZ];
    __shared__ ushort Ps[128][72];

    const int blk = blockIdx.x;
    const int grp = blk & 63, qt = blk >> 6;
    const int h = grp & 7, b = grp >> 3;
    const int i0 = qt << 7;
    const int t = threadIdx.x;
    const int w = t >> 6, lane = t & 63, lo = lane & 15, hi = lane >> 4;
    const int gsh = lane & 48;
    const size_t base = (size_t)b * SEQ * 768;

    const short8 aQ = *(const short8*)(qkv + base + (size_t)(i0 + 16*w + lo) * 768 + h * HDIM + hi * 8);
    short8 ones;
    #pragma unroll
    for (int e = 0; e < 8; e++) ones[e] = (short)0x3F80;

    const int tt = t & 255;
    const int srow = tt >> 2, scb = (tt & 3) << 3;
    const bool isK = t < 256;
    const int vcol = (srow & 32) | ((srow & 15) << 1) | ((srow >> 4) & 1);
    {
        const ushort* p0 = qkv + base + (size_t)srow * 768 + h * HDIM + (isK ? 256 : 512) + scb;
        short8 v0 = *(const short8*)p0;
        if (isK) *(short8*)&Ks[0][srow][scb] = v0;
        else {
            #pragma unroll
            for (int e = 0; e < 8; e++) Vt[0][vt_idx(scb + e, vcol)] = (ushort)v0[e];
        }
    }

    float m_run[4], l_run[4];
    f32x4 O0 = {0.f, 0.f, 0.f, 0.f}, O1 = {0.f, 0.f, 0.f, 0.f};
    #pragma unroll
    for (int r = 0; r < 4; r++) { m_run[r] = -3.0e38f; l_run[r] = 0.f; }
    const f32x4 zero = {0.f, 0.f, 0.f, 0.f};

    short8 reg;
    for (int it = 0; it < 16; it++) {
        const int cur = it & 1;
        if (it < 15)
            reg = *(const short8*)(qkv + base + (size_t)((it + 1) * 64 + srow) * 768
                                   + h * HDIM + (isK ? 256 : 512) + scb);
        __syncthreads();

        f32x4 S[4];
        #pragma unroll
        for (int jt = 0; jt < 4; jt++) {
            short8 bK = *(const short8*)&Ks[cur][16 * jt + lo][hi * 8];
            S[jt] = __builtin_amdgcn_mfma_f32_16x16x32_bf16(aQ, bK, zero, 0, 0, 0);
        }

        float mxl[4];
        bool any = false;
        #pragma unroll
        for (int r = 0; r < 4; r++) {
            mxl[r] = fmaxf(fmaxf(S[0][r], S[1][r]), fmaxf(S[2][r], S[3][r]));
            any = any || (mxl[r] > m_run[r] + 8.f);
        }
        unsigned long long bal = __ballot(any);
        if ((bal >> gsh) & 0xffffULL) {
            #pragma unroll
            for (int r = 0; r < 4; r++) {
                float mx = mxl[r];
                #pragma unroll
                for (int off = 8; off; off >>= 1) mx = fmaxf(mx, __shfl_xor(mx, off, 16));
                float mnew = fmaxf(m_run[r], mx);
                float sc = exp2f(m_run[r] - mnew);
                m_run[r] = mnew;
                l_run[r] *= sc; O0[r] *= sc; O1[r] *= sc;
            }
        }
        #pragma unroll
        for (int r = 0; r < 4; r++) {
            const int row = 16 * w + 4 * hi + r;
            unsigned u01 = cvt_pk_bf16(exp2f(S[0][r] - m_run[r]), exp2f(S[1][r] - m_run[r]));
            unsigned u23 = cvt_pk_bf16(exp2f(S[2][r] - m_run[r]), exp2f(S[3][r] - m_run[r]));
            *(unsigned*)&Ps[row][2 * lo]      = u01;
            *(unsigned*)&Ps[row][32 + 2 * lo] = u23;
        }

        f32x4 O2 = zero;
        #pragma unroll
        for (int kt = 0; kt < 2; kt++) {
            short8 aP  = *(const short8*)&Ps[16 * w + lo][32 * kt + hi * 8];
            short8 bV0 = *(const short8*)&Vt[cur][vt_idx(lo,      32 * kt + hi * 8)];
            short8 bV1 = *(const short8*)&Vt[cur][vt_idx(16 + lo, 32 * kt + hi * 8)];
            O0 = __builtin_amdgcn_mfma_f32_16x16x32_bf16(aP, bV0, O0, 0, 0, 0);
            O1 = __builtin_amdgcn_mfma_f32_16x16x32_bf16(aP, bV1, O1, 0, 0, 0);
            O2 = __builtin_amdgcn_mfma_f32_16x16x32_bf16(aP, ones, O2, 0, 0, 0);
        }
        #pragma unroll
        for (int r = 0; r < 4; r++) l_run[r] += O2[r];

        if (it < 15) {
            if (isK) *(short8*)&Ks[cur ^ 1][srow][scb] = reg;
            else {
                #pragma unroll
                for (int e = 0; e < 8; e++) Vt[cur ^ 1][vt_idx(scb + e, vcol)] = (ushort)reg[e];
            }
        }
    }

    #pragma unroll
    for (int r = 0; r < 4; r++) {
        float inv = 1.0f / l_run[r];
        size_t row = (size_t)b * SEQ + i0 + 16 * w + 4 * hi + r;
        ctxb[row * DM + h * HDIM + lo]      = f2bf(O0[r] * inv);
        ctxb[row * DM + h * HDIM + 16 + lo] = f2bf(O1[r] * inv);
    }
}

extern "C" void kernel_launch(void* const* d_in, const int* in_sizes, int n_in,
                              void* d_out, int out_size, void* d_ws, size_t ws_size,
                              hipStream_t stream)
{
    const float* src        = (const float*)d_in[0];
    const int*   adj        = (const int*)  d_in[1];
    const float* W_gat      = (const float*)d_in[2];
    const float* a_gat      = (const float*)d_in[3];
    const float* in_proj_w  = (const float*)d_in[4];
    const float* in_proj_b  = (const float*)d_in[5];
    const float* out_proj_w = (const float*)d_in[6];
    const float* out_proj_b = (const float*)d_in[7];
    const float* lin1_w     = (const float*)d_in[8];
    const float* lin1_b     = (const float*)d_in[9];
    const float* lin2_w     = (const float*)d_in[10];
    const float* lin2_b     = (const float*)d_in[11];
    const float* ln1_g      = (const float*)d_in[12];
    const float* ln1_b_     = (const float*)d_in[13];
    const float* ln2_g      = (const float*)d_in[14];
    const float* ln2_b_     = (const float*)d_in[15];
    const float* ln3_g      = (const float*)d_in[16];
    const float* ln3_b_     = (const float*)d_in[17];

    char* base = (char*)d_ws;
    const size_t MB = 1024 * 1024;
    ushort* tmpb  = (ushort*)(base + 0 * MB);    // 4 MB (bf16 pre-LN GEMM out)
    ushort* P_bf  = (ushort*)(base + 4 * MB);    // 16 MB (then qkvb / ff1b)
    ushort* qkvb  = (ushort*)(base + 4 * MB);
    ushort* ff1b  = (ushort*)(base + 4 * MB);
    ushort* srcb  = (ushort*)(base + 36 * MB);   // 4 MB
    ushort* WhTb  = (ushort*)(base + 40 * MB);   // 4 MB ([256][8192])
    ushort* xb    = (ushort*)(base + 44 * MB);   // 4 MB
    ushort* yb    = (ushort*)(base + 48 * MB);   // 4 MB
    ushort* ctxb  = (ushort*)(base + 52 * MB);   // 4 MB
    float*  f1    = (float*) (base + 56 * MB);
    float*  f2    = f1 + ROWS;
    float*  w1    = f2 + ROWS;
    float*  w2    = w1 + DM;
    ushort* wgTb  = (ushort*)(base + 57 * MB);
    ushort* ipwb  = wgTb + 65536;
    ushort* opwb  = ipwb + 196608;
    ushort* l1wb  = opwb + 65536;
    ushort* l2wb  = l1wb + 524288;

    dim3 b256(256);

    CastArgs ca;
    ca.in[0] = src;       ca.out[0] = srcb; ca.n4[0] = 2097152 / 4;
    ca.in[1] = in_proj_w; ca.out[1] = ipwb; ca.n4[1] = 196608 / 4;
    ca.in[2] = out_proj_w;ca.out[2] = opwb; ca.n4[2] = 65536 / 4;
    ca.in[3] = lin1_w;    ca.out[3] = l1wb; ca.n4[3] = 524288 / 4;
    ca.in[4] = lin2_w;    ca.out[4] = l2wb; ca.n4[4] = 524288 / 4;
    prep_k<<<CAST_BLKS + 64 + 64, b256, 0, stream>>>(ca, W_gat, a_gat, wgTb, w1, w2);

    // --- GAT: WhT GEMM + f12 in one dispatch (independent workloads) ---
    fwt_k<<<512 + ROWS / 4, b256, 0, stream>>>(wgTb, srcb, WhTb, src, w1, w2, f1, f2);
    gat_sm_k<<<ROWS / 4, b256, 0, stream>>>(adj, f1, f2, P_bf);
    gemm_bf<3, 64, 64><<<dim3(DM/64, SEQ/64, 8), b256, 0, stream>>>(P_bf, WhTb, nullptr, tmpb,
                                                                    DM, SEQ, ROWS,
                                                                    (long long)SEQ * SEQ, (long long)SEQ, (long long)SEQ * DM);
    ln_k<0><<<ROWS / 4, b256, 0, stream>>>(src, nullptr, tmpb, ln1_g, ln1_b_, nullptr, xb);

    // --- MHA ---
    gemm_bf<6, 128, 64><<<dim3(768/64, ROWS/128, 1), b256, 0, stream>>>(xb, ipwb, in_proj_b, qkvb,
                                                                        768, DM, DM, 0, 0, 0);
    mha_k<<<BATCH * NH * (SEQ / 128), dim3(512), 0, stream>>>(qkvb, ctxb);
    gemm_bf<1, 64, 64><<<dim3(DM/64, ROWS/64, 1), b256, 0, stream>>>(ctxb, opwb, out_proj_b, tmpb,
                                                                     DM, DM, DM, 0, 0, 0);
    ln_k<1><<<ROWS / 4, b256, 0, stream>>>(nullptr, xb, tmpb, ln2_g, ln2_b_, nullptr, yb);

    // --- FFN ---
    gemm_bf<2, 128, 128><<<dim3(DF/128, ROWS/128, 1), b256, 0, stream>>>(yb, l1wb, lin1_b, ff1b,
                                                                         DF, DM, DM, 0, 0, 0);
    gemm_bf<1, 64, 64><<<dim3(DM/64, ROWS/64, 1), b256, 0, stream>>>(ff1b, l2wb, lin2_b, tmpb,
                                                                     DM, DF, DF, 0, 0, 0);
    ln_k<2><<<ROWS / 4, b256, 0, stream>>>(nullptr, yb, tmpb, ln3_g, ln3_b_, (float*)d_out, nullptr);
}